// Round 16
// baseline (28.398 us; speedup 1.0000x reference)
//
#include <hip/hip_runtime.h>

// Problem constants (fixed by the reference file): B=8, N=4096.
#define NN 4096
#define BB 8
#define JT 4          // ISNet rows per block
#define BT 4          // batches per wave
#define KS 2          // in-block k-splits
#define KH (NN / KS)  // 2048 k per wave

typedef float v2f __attribute__((ext_vector_type(2)));

// R13 tile (byte-lean: JT x BT = 16 pairs/lane, 256 KB/block VMEM, -33% vs
// R6/R14) combined with R14 math (packed f32 + one f64 fma per 8 factors,
// -40% VALU). Rounds 12-15 showed each lever alone is neutral -> the system
// sits at max(VMEM-return, VALU) with both ~balanced at ~20 µs; this round
// lowers BOTH in one kernel.
// Wave w -> (bg = w&1, ks = w>>1): rows j0..j0+3, batches bg*4..+3,
// k in [ks*KH, (ks+1)*KH). Single-buffered loads (R13 compiled clean;
// R10's double-buffered variant spilled). In-block k-split combine via
// 512 B LDS + one barrier. Factor scheme: z in f32, q4 per float4 (exact
// pairwise fmaf), q8 = q4_even ⊕ q4_odd in f32, prod = fma(-q8, prod, prod).

__global__ __launch_bounds__(256, 4) void epi_kernel(
    const float* __restrict__ state,    // [B,4,N]
    const float* __restrict__ ISNet,    // [N,N]
    const float* __restrict__ psMatrix, // [4,4]
    const float* __restrict__ U,        // [N]
    float* __restrict__ out)            // [B,4,N]
{
    const int j0   = blockIdx.x * JT;
    const int tid  = threadIdx.x;
    const int wave = tid >> 6;
    const int lane = tid & 63;
    const int bg   = wave & 1;
    const int ks   = wave >> 1;
    const int b0   = bg * BT;
    const int kb   = ks * KH;

    __shared__ double red[KS][JT][BB];   // 512 B

    const float p01 = psMatrix[1];       // psM[0,1] == psMatrix[0,1]

    float  cf[JT][BT];
    float  qp[JT][BT];                   // pending q4 from even stages
    double prod[JT][BT];
    #pragma unroll
    for (int jj = 0; jj < JT; ++jj) {
        #pragma unroll
        for (int bi = 0; bi < BT; ++bi) {
            cf[jj][bi]   = state[(size_t)(b0 + bi) * 4 * NN + (j0 + jj)] * p01;
            prod[jj][bi] = 1.0;
            qp[jj][bi]   = 0.0f;
        }
    }

    const float4* __restrict__ w_0 = (const float4*)(ISNet + (size_t)(j0 + 0) * NN + kb);
    const float4* __restrict__ w_1 = (const float4*)(ISNet + (size_t)(j0 + 1) * NN + kb);
    const float4* __restrict__ w_2 = (const float4*)(ISNet + (size_t)(j0 + 2) * NN + kb);
    const float4* __restrict__ w_3 = (const float4*)(ISNet + (size_t)(j0 + 3) * NN + kb);
    const float4* __restrict__ i_0 = (const float4*)(state + ((size_t)(b0 + 0) * 4 + 2) * NN + kb);
    const float4* __restrict__ i_1 = (const float4*)(state + ((size_t)(b0 + 1) * 4 + 2) * NN + kb);
    const float4* __restrict__ i_2 = (const float4*)(state + ((size_t)(b0 + 2) * 4 + 2) * NN + kb);
    const float4* __restrict__ i_3 = (const float4*)(state + ((size_t)(b0 + 3) * 4 + 2) * NN + kb);

#define COMP(JJ, BI, WV, IV, ODD)                                              \
    do {                                                                       \
        const v2f c2  = {cf[JJ][BI], cf[JJ][BI]};                              \
        const v2f z01 = (c2 * (v2f){WV.x, WV.y}) * (v2f){IV.x, IV.y};          \
        const v2f z23 = (c2 * (v2f){WV.z, WV.w}) * (v2f){IV.z, IV.w};          \
        const v2f q2  = __builtin_elementwise_fma(-z01, z23, z01 + z23);       \
        const float q4 = fmaf(-q2.x, q2.y, q2.x + q2.y);                       \
        if (!(ODD)) {                                                          \
            qp[JJ][BI] = q4;                                                   \
        } else {                                                               \
            const float q8 = fmaf(-qp[JJ][BI], q4, qp[JJ][BI] + q4);           \
            prod[JJ][BI] = fma(-(double)q8, prod[JJ][BI], prod[JJ][BI]);       \
        }                                                                      \
    } while (0)

    #pragma unroll
    for (int it = 0; it < KH / 256; ++it) {   // 8 stages of 256 k
        const int x = lane + it * 64;
        const float4 wv0 = w_0[x], wv1 = w_1[x], wv2 = w_2[x], wv3 = w_3[x];
        const float4 iv0 = i_0[x], iv1 = i_1[x], iv2 = i_2[x], iv3 = i_3[x];
        const int odd = it & 1;

        COMP(0, 0, wv0, iv0, odd); COMP(0, 1, wv0, iv1, odd);
        COMP(0, 2, wv0, iv2, odd); COMP(0, 3, wv0, iv3, odd);
        COMP(1, 0, wv1, iv0, odd); COMP(1, 1, wv1, iv1, odd);
        COMP(1, 2, wv1, iv2, odd); COMP(1, 3, wv1, iv3, odd);
        COMP(2, 0, wv2, iv0, odd); COMP(2, 1, wv2, iv1, odd);
        COMP(2, 2, wv2, iv2, odd); COMP(2, 3, wv2, iv3, odd);
        COMP(3, 0, wv3, iv0, odd); COMP(3, 1, wv3, iv1, odd);
        COMP(3, 2, wv3, iv2, odd); COMP(3, 3, wv3, iv3, odd);
    }
#undef COMP

    // 3 XOR-butterfly levels: every lane holds the partial over its mod-8
    // residue class for all 16 (jj,bi) values.
    #pragma unroll
    for (int off = 32; off >= 8; off >>= 1) {
        #pragma unroll
        for (int jj = 0; jj < JT; ++jj) {
            #pragma unroll
            for (int bi = 0; bi < BT; ++bi)
                prod[jj][bi] *= __shfl_xor(prod[jj][bi], off, 64);
        }
    }

    // 8-lane group g reduces values (jj = g>>1, bi = (g&1)*2 + {0,1}).
    const int g = lane >> 3;
    double v0 = prod[0][0], v1 = prod[0][1];
    v0 = (g == 1) ? prod[0][2] : v0;  v1 = (g == 1) ? prod[0][3] : v1;
    v0 = (g == 2) ? prod[1][0] : v0;  v1 = (g == 2) ? prod[1][1] : v1;
    v0 = (g == 3) ? prod[1][2] : v0;  v1 = (g == 3) ? prod[1][3] : v1;
    v0 = (g == 4) ? prod[2][0] : v0;  v1 = (g == 4) ? prod[2][1] : v1;
    v0 = (g == 5) ? prod[2][2] : v0;  v1 = (g == 5) ? prod[2][3] : v1;
    v0 = (g == 6) ? prod[3][0] : v0;  v1 = (g == 6) ? prod[3][1] : v1;
    v0 = (g == 7) ? prod[3][2] : v0;  v1 = (g == 7) ? prod[3][3] : v1;
    v0 *= __shfl_down(v0, 4, 64);  v1 *= __shfl_down(v1, 4, 64);
    v0 *= __shfl_down(v0, 2, 64);  v1 *= __shfl_down(v1, 2, 64);
    v0 *= __shfl_down(v0, 1, 64);  v1 *= __shfl_down(v1, 1, 64);

    if ((lane & 7) == 0) {
        const int jj  = g >> 1;
        const int bi0 = (g & 1) * 2;
        red[ks][jj][b0 + bi0 + 0] = v0;
        red[ks][jj][b0 + bi0 + 1] = v1;
    }
    __syncthreads();

    if (tid < JT * BB) {   // 32 threads: (jj, b)
        const int jj = tid >> 3, b = tid & 7;
        const int j  = j0 + jj;
        const double tot = red[0][jj][b] * red[1][jj][b];
        const double ps1 = 1.0 - tot;

        // expand_psMatrix in f64
        double pm[4][4];
        #pragma unroll
        for (int r = 0; r < 4; ++r) {
            double s = 0.0;
            #pragma unroll
            for (int q = 0; q < 4; ++q) {
                pm[r][q] = (double)psMatrix[r * 4 + q];
                s += pm[r][q];
            }
            pm[r][r] += (1.0 - s);
        }

        double st[4];
        #pragma unroll
        for (int r = 0; r < 4; ++r)
            st[r] = (double)state[(size_t)b * 4 * NN + r * NN + j];

        const double S = st[0];
        const double ps10[4] = {1.0 - ps1, ps1, 0.0, 0.0};

        double P[4];
        #pragma unroll
        for (int i = 0; i < 4; ++i) {
            double acc = S * ps10[i];
            #pragma unroll
            for (int r = 1; r < 4; ++r)
                acc += pm[r][i] * st[r];
            P[i] = acc;
        }

        double u = (double)U[j];
        #pragma unroll
        for (int i = 0; i < 4; ++i) {
            u -= P[i];
            const double s = (u < 0.0) ? 1.0 : 0.0;
            out[(size_t)b * 4 * NN + i * NN + j] = (float)s;
            u += s;
        }
    }
}

extern "C" void kernel_launch(void* const* d_in, const int* in_sizes, int n_in,
                              void* d_out, int out_size, void* d_ws, size_t ws_size,
                              hipStream_t stream) {
    const float* state    = (const float*)d_in[0];  // [8,4,4096]
    const float* ISNet    = (const float*)d_in[1];  // [4096,4096]
    const float* psMatrix = (const float*)d_in[2];  // [4,4]
    const float* U        = (const float*)d_in[3];  // [4096]
    float* out            = (float*)d_out;          // [8,4,4096]

    epi_kernel<<<NN / JT, 256, 0, stream>>>(state, ISNet, psMatrix, U, out);
}